// Round 2
// baseline (947.478 us; speedup 1.0000x reference)
//
#include <hip/hip_runtime.h>
#include <stdint.h>

#define F_DIM 128
#define H_DIM 64
#define K_DIM 16
#define NEG_SLOPE 0.2f

// ---- CSR construction --------------------------------------------------
__global__ void k_degree(const int* __restrict__ dst, int* __restrict__ counts, int E) {
    int e = blockIdx.x * 256 + threadIdx.x;
    if (e < E) atomicAdd(&counts[dst[e]], 1);
}

__global__ void k_scanA(const int* __restrict__ counts, int* __restrict__ tmp,
                        int* __restrict__ bsum, int N) {
    __shared__ int sh[256];
    int t = threadIdx.x, b = blockIdx.x;
    int base = b * 1024 + t * 4;
    int c0 = (base + 0 < N) ? counts[base + 0] : 0;
    int c1 = (base + 1 < N) ? counts[base + 1] : 0;
    int c2 = (base + 2 < N) ? counts[base + 2] : 0;
    int c3 = (base + 3 < N) ? counts[base + 3] : 0;
    int s = c0 + c1 + c2 + c3;
    sh[t] = s;
    __syncthreads();
    for (int off = 1; off < 256; off <<= 1) {
        int v = (t >= off) ? sh[t - off] : 0;
        __syncthreads();
        sh[t] += v;
        __syncthreads();
    }
    int excl = sh[t] - s;
    int r0 = excl + c0, r1 = r0 + c1, r2 = r1 + c2, r3 = r2 + c3;
    if (base + 0 < N) tmp[base + 0] = r0;
    if (base + 1 < N) tmp[base + 1] = r1;
    if (base + 2 < N) tmp[base + 2] = r2;
    if (base + 3 < N) tmp[base + 3] = r3;
    if (t == 255) bsum[b] = sh[255];
}

__global__ void k_scanB(int* __restrict__ bsum, int NB) {
    __shared__ int sh[256];
    int t = threadIdx.x;
    int v = (t < NB) ? bsum[t] : 0;
    sh[t] = v;
    __syncthreads();
    for (int off = 1; off < 256; off <<= 1) {
        int x = (t >= off) ? sh[t - off] : 0;
        __syncthreads();
        sh[t] += x;
        __syncthreads();
    }
    if (t < NB) bsum[t] = sh[t];
}

__global__ void k_scanC(const int* __restrict__ tmp, const int* __restrict__ bsum,
                        int* __restrict__ rowptr, int N) {
    int i = blockIdx.x * 256 + threadIdx.x;
    if (i < N) {
        int b = i >> 10;
        int off = (b > 0) ? bsum[b - 1] : 0;
        rowptr[i + 1] = tmp[i] + off;
    }
    if (i == 0) rowptr[0] = 0;
}

__global__ void k_fill(const int* __restrict__ src, const int* __restrict__ dst,
                       const int* __restrict__ rowptr, int* __restrict__ fillc,
                       int* __restrict__ col, int E) {
    int e = blockIdx.x * 256 + threadIdx.x;
    if (e < E) {
        int d = dst[e];
        int pos = rowptr[d] + atomicAdd(&fillc[d], 1);
        col[pos] = src[e];
    }
}

// ---- Layer GEMMs -------------------------------------------------------
// xl = X @ Wl, xr = X @ Wr   (X: [N,128] f32, W: [128,64] f32)
__global__ void k_gemm1(const float* __restrict__ X,
                        const float* __restrict__ Wl,
                        const float* __restrict__ Wr,
                        float* __restrict__ xl, float* __restrict__ xr, int N) {
    int n = (int)((blockIdx.x * (unsigned)blockDim.x + threadIdx.x) >> 6);
    int lane = threadIdx.x & 63;
    if (n >= N) return;
    const float* xrow = X + (long)n * F_DIM;
    float al = 0.f, ar = 0.f;
#pragma unroll 8
    for (int k = 0; k < F_DIM; ++k) {
        float xs = xrow[k];
        al += xs * Wl[k * H_DIM + lane];
        ar += xs * Wr[k * H_DIM + lane];
    }
    xl[(long)n * H_DIM + lane] = al;
    xr[(long)n * H_DIM + lane] = ar;
}

// xl2 = H @ W2l, xr2 = H @ W2r  (H: [N,64] f32, W2: [64,16] f32)
__global__ void k_gemm2(const float* __restrict__ Hm,
                        const float* __restrict__ Wl,
                        const float* __restrict__ Wr,
                        float* __restrict__ xl, float* __restrict__ xr, int N) {
    int n = (int)((blockIdx.x * (unsigned)blockDim.x + threadIdx.x) >> 6);
    int lane = threadIdx.x & 63;
    if (n >= N) return;
    int j = lane & 15, kg = lane >> 4;
    float al = 0.f, ar = 0.f;
#pragma unroll
    for (int i = 0; i < 16; ++i) {
        int k = kg * 16 + i;
        float hs = Hm[(long)n * H_DIM + k];
        al += hs * Wl[k * K_DIM + j];
        ar += hs * Wr[k * K_DIM + j];
    }
    al += __shfl_xor(al, 16); al += __shfl_xor(al, 32);
    ar += __shfl_xor(ar, 16); ar += __shfl_xor(ar, 32);
    if (kg == 0) {
        xl[(long)n * K_DIM + j] = al;
        xr[(long)n * K_DIM + j] = ar;
    }
}

// ---- Edge kernels: online softmax over incoming edges ------------------
// Layer 1: one wave per node, lane = h dim (64). Self-loop processed first.
__global__ void k_edge1(const float* __restrict__ xl, const float* __restrict__ xr,
                        const float* __restrict__ a1, const float* __restrict__ b1,
                        const int* __restrict__ rowptr, const int* __restrict__ col,
                        float* __restrict__ hout, int N) {
    int n = (int)((blockIdx.x * (unsigned)blockDim.x + threadIdx.x) >> 6);
    int lane = threadIdx.x & 63;
    if (n >= N) return;
    float av = a1[lane];
    float xrd = xr[(long)n * H_DIM + lane];
    float xls = xl[(long)n * H_DIM + lane];
    float t = xls + xrd; t = (t > 0.f) ? t : NEG_SLOPE * t;
    float p = av * t;
#pragma unroll
    for (int off = 32; off; off >>= 1) p += __shfl_xor(p, off);
    float m = p, l = 1.f, o = xls;
    int jb = rowptr[n], je = rowptr[n + 1];
    for (int j = jb; j < je; ++j) {
        int s = col[j];
        float xv = xl[(long)s * H_DIM + lane];
        float tt = xv + xrd; tt = (tt > 0.f) ? tt : NEG_SLOPE * tt;
        float e = av * tt;
#pragma unroll
        for (int off = 32; off; off >>= 1) e += __shfl_xor(e, off);
        if (e > m) {                 // wave-uniform branch (e identical on all lanes)
            float c = __expf(m - e);
            l = l * c + 1.f;
            o = o * c + xv;
            m = e;
        } else {
            float c = __expf(e - m);
            l += c;
            o += c * xv;
        }
    }
    float h = o / l + b1[lane];
    h = (h > 0.f) ? h : (__expf(h) - 1.f);   // ELU(alpha=1)
    hout[(long)n * H_DIM + lane] = h;
}

// Layer 2 + row softmax: one wave per node, lanes mirror j = lane & 15.
__global__ void k_edge2(const float* __restrict__ xl, const float* __restrict__ xr,
                        const float* __restrict__ a2, const float* __restrict__ b2v,
                        const int* __restrict__ rowptr, const int* __restrict__ col,
                        float* __restrict__ out, int N) {
    int n = (int)((blockIdx.x * (unsigned)blockDim.x + threadIdx.x) >> 6);
    int lane = threadIdx.x & 63;
    if (n >= N) return;
    int j = lane & 15;
    float av = a2[j];
    float xrd = xr[(long)n * K_DIM + j];
    float xls = xl[(long)n * K_DIM + j];
    float t = xls + xrd; t = (t > 0.f) ? t : NEG_SLOPE * t;
    float p = av * t;
#pragma unroll
    for (int off = 8; off; off >>= 1) p += __shfl_xor(p, off, 16);
    float m = p, l = 1.f, o = xls;
    int jb = rowptr[n], je = rowptr[n + 1];
    for (int jj = jb; jj < je; ++jj) {
        int s = col[jj];
        float xv = xl[(long)s * K_DIM + j];
        float tt = xv + xrd; tt = (tt > 0.f) ? tt : NEG_SLOPE * tt;
        float e = av * tt;
#pragma unroll
        for (int off = 8; off; off >>= 1) e += __shfl_xor(e, off, 16);
        if (e > m) {
            float c = __expf(m - e);
            l = l * c + 1.f;
            o = o * c + xv;
            m = e;
        } else {
            float c = __expf(e - m);
            l += c;
            o += c * xv;
        }
    }
    float z = o / l + b2v[j];
    float mx = z;
#pragma unroll
    for (int off = 8; off; off >>= 1) mx = fmaxf(mx, __shfl_xor(mx, off, 16));
    float ez = __expf(z - mx);
    float ss = ez;
#pragma unroll
    for (int off = 8; off; off >>= 1) ss += __shfl_xor(ss, off, 16);
    if (lane < 16) out[(long)n * K_DIM + j] = ez / ss;
}

// ---- launch ------------------------------------------------------------
extern "C" void kernel_launch(void* const* d_in, const int* in_sizes, int n_in,
                              void* d_out, int out_size, void* d_ws, size_t ws_size,
                              hipStream_t stream) {
    const float* X   = (const float*)d_in[0];
    const int*   ei  = (const int*)d_in[1];
    const float* W1l = (const float*)d_in[3];
    const float* W1r = (const float*)d_in[4];
    const float* a1  = (const float*)d_in[5];
    const float* b1  = (const float*)d_in[6];
    const float* W2l = (const float*)d_in[7];
    const float* W2r = (const float*)d_in[8];
    const float* a2  = (const float*)d_in[9];
    const float* b2  = (const float*)d_in[10];

    int N = in_sizes[0] / F_DIM;
    int E = in_sizes[1] / 2;
    const int* srcv = ei;
    const int* dstv = ei + E;

    char* w = (char*)d_ws;
    size_t off = 0;
    auto alloc = [&](size_t bytes) -> char* {
        char* p = w + off;
        off = (off + bytes + 255) & ~(size_t)255;
        return p;
    };
    int* counts = (int*)alloc((size_t)2 * N * sizeof(int));  // counts + fill, one memset
    int* fillc  = counts + N;
    int* rowptr = (int*)alloc((size_t)(N + 1) * sizeof(int));
    int* bsum   = (int*)alloc(256 * sizeof(int));
    int* tmp    = (int*)alloc((size_t)N * sizeof(int));
    int* col    = (int*)alloc((size_t)E * sizeof(int));
    float* xl1 = (float*)alloc((size_t)N * H_DIM * sizeof(float));
    float* xr1 = (float*)alloc((size_t)N * H_DIM * sizeof(float));
    float* h1  = (float*)alloc((size_t)N * H_DIM * sizeof(float));
    float* xl2 = (float*)alloc((size_t)N * K_DIM * sizeof(float));
    float* xr2 = (float*)alloc((size_t)N * K_DIM * sizeof(float));

    hipMemsetAsync(counts, 0, (size_t)2 * N * sizeof(int), stream);

    const int tb = 256;
    k_degree<<<(E + tb - 1) / tb, tb, 0, stream>>>(dstv, counts, E);
    int nbA = (N + 1023) / 1024;
    k_scanA<<<nbA, 256, 0, stream>>>(counts, tmp, bsum, N);
    k_scanB<<<1, 256, 0, stream>>>(bsum, nbA);
    k_scanC<<<(N + tb - 1) / tb, tb, 0, stream>>>(tmp, bsum, rowptr, N);
    k_fill<<<(E + tb - 1) / tb, tb, 0, stream>>>(srcv, dstv, rowptr, fillc, col, E);

    int nodeBlocks = (N + 3) / 4;  // 4 waves (nodes) per 256-thread block
    k_gemm1<<<nodeBlocks, 256, 0, stream>>>(X, W1l, W1r, xl1, xr1, N);
    k_edge1<<<nodeBlocks, 256, 0, stream>>>(xl1, xr1, a1, b1, rowptr, col, h1, N);
    k_gemm2<<<nodeBlocks, 256, 0, stream>>>(h1, W2l, W2r, xl2, xr2, N);
    k_edge2<<<nodeBlocks, 256, 0, stream>>>(xl2, xr2, a2, b2, rowptr, col,
                                            (float*)d_out, N);
}

// Round 3
// 534.448 us; speedup vs baseline: 1.7728x; 1.7728x over previous
//
#include <hip/hip_runtime.h>
#include <stdint.h>

#define F_DIM 128
#define H_DIM 64
#define K_DIM 16
#define NEG_SLOPE 0.2f

// ---- CSR construction --------------------------------------------------
__global__ void k_degree(const int* __restrict__ dst, int* __restrict__ counts, int E) {
    int e = blockIdx.x * 256 + threadIdx.x;
    if (e < E) atomicAdd(&counts[dst[e]], 1);
}

__global__ void k_scanA(const int* __restrict__ counts, int* __restrict__ tmp,
                        int* __restrict__ bsum, int N) {
    __shared__ int sh[256];
    int t = threadIdx.x, b = blockIdx.x;
    int base = b * 1024 + t * 4;
    int c0 = (base + 0 < N) ? counts[base + 0] : 0;
    int c1 = (base + 1 < N) ? counts[base + 1] : 0;
    int c2 = (base + 2 < N) ? counts[base + 2] : 0;
    int c3 = (base + 3 < N) ? counts[base + 3] : 0;
    int s = c0 + c1 + c2 + c3;
    sh[t] = s;
    __syncthreads();
    for (int off = 1; off < 256; off <<= 1) {
        int v = (t >= off) ? sh[t - off] : 0;
        __syncthreads();
        sh[t] += v;
        __syncthreads();
    }
    int excl = sh[t] - s;
    int r0 = excl + c0, r1 = r0 + c1, r2 = r1 + c2, r3 = r2 + c3;
    if (base + 0 < N) tmp[base + 0] = r0;
    if (base + 1 < N) tmp[base + 1] = r1;
    if (base + 2 < N) tmp[base + 2] = r2;
    if (base + 3 < N) tmp[base + 3] = r3;
    if (t == 255) bsum[b] = sh[255];
}

__global__ void k_scanB(int* __restrict__ bsum, int NB) {
    __shared__ int sh[256];
    int t = threadIdx.x;
    int v = (t < NB) ? bsum[t] : 0;
    sh[t] = v;
    __syncthreads();
    for (int off = 1; off < 256; off <<= 1) {
        int x = (t >= off) ? sh[t - off] : 0;
        __syncthreads();
        sh[t] += x;
        __syncthreads();
    }
    if (t < NB) bsum[t] = sh[t];
}

__global__ void k_scanC(const int* __restrict__ tmp, const int* __restrict__ bsum,
                        int* __restrict__ rowptr, int N) {
    int i = blockIdx.x * 256 + threadIdx.x;
    if (i < N) {
        int b = i >> 10;
        int off = (b > 0) ? bsum[b - 1] : 0;
        rowptr[i + 1] = tmp[i] + off;
    }
    if (i == 0) rowptr[0] = 0;
}

__global__ void k_fill(const int* __restrict__ src, const int* __restrict__ dst,
                       const int* __restrict__ rowptr, int* __restrict__ fillc,
                       int* __restrict__ col, int E) {
    int e = blockIdx.x * 256 + threadIdx.x;
    if (e < E) {
        int d = dst[e];
        int pos = rowptr[d] + atomicAdd(&fillc[d], 1);
        col[pos] = src[e];
    }
}

// ---- Layer 1 GEMM: LDS-tiled.  Y[N x 128] = X[N x 128] @ [Wl | Wr]  ----
// Tile: 64 nodes x 128 cols, K split into 2 phases of 64.
// LDS: Ws 64x128 (32 KB) + Xs 64x68 (17.4 KB) = 49.4 KB -> 2 blocks/CU.
#define G1_NT 64
#define G1_XS 68   // 64 + 4 pad (keeps float4 align, breaks bank aliasing)
__global__ __launch_bounds__(256) void k_gemm1t(
        const float* __restrict__ X, const float* __restrict__ Wl,
        const float* __restrict__ Wr,
        float* __restrict__ xl, float* __restrict__ xr, int N) {
    __shared__ float Ws[64 * 128];
    __shared__ float Xs[G1_NT * G1_XS];
    int t = threadIdx.x;
    int n0 = blockIdx.x * G1_NT;
    int validRows = N - n0; if (validRows > G1_NT) validRows = G1_NT;
    int cg = t & 31;   // 32 col-groups x 4 cols = 128 cols
    int ng = t >> 5;   // 8 node-groups x 8 nodes = 64 nodes
    float acc[8][4];
#pragma unroll
    for (int i = 0; i < 8; ++i)
#pragma unroll
        for (int c = 0; c < 4; ++c) acc[i][c] = 0.f;

    for (int kt = 0; kt < 2; ++kt) {
        int kbase = kt * 64;
        // stage W half: Wl/Wr rows kbase..kbase+63 -> Ws[kk][0..63 | 64..127]
        // each matrix half: 64x64 floats = 1024 float4
        for (int i = t; i < 1024; i += 256) {
            int kk = i >> 4, c = (i & 15) << 2;
            *(float4*)&Ws[kk * 128 + c] =
                *(const float4*)&Wl[(kbase + kk) * H_DIM + c];
            *(float4*)&Ws[kk * 128 + 64 + c] =
                *(const float4*)&Wr[(kbase + kk) * H_DIM + c];
        }
        // stage X half: rows n0..n0+63, k kbase..kbase+63 -> 64x16 float4
        for (int i = t; i < 1024; i += 256) {
            int r = i >> 4, c = (i & 15) << 2;
            float4 v = {0.f, 0.f, 0.f, 0.f};
            if (r < validRows)
                v = *(const float4*)&X[(long)(n0 + r) * F_DIM + kbase + c];
            *(float4*)&Xs[r * G1_XS + c] = v;
        }
        __syncthreads();
        for (int kk = 0; kk < 64; kk += 4) {
            float4 w0 = *(const float4*)&Ws[(kk + 0) * 128 + (cg << 2)];
            float4 w1 = *(const float4*)&Ws[(kk + 1) * 128 + (cg << 2)];
            float4 w2 = *(const float4*)&Ws[(kk + 2) * 128 + (cg << 2)];
            float4 w3 = *(const float4*)&Ws[(kk + 3) * 128 + (cg << 2)];
#pragma unroll
            for (int i = 0; i < 8; ++i) {
                float4 xv = *(const float4*)&Xs[(ng * 8 + i) * G1_XS + kk];
                acc[i][0] = fmaf(xv.w, w3.x, fmaf(xv.z, w2.x, fmaf(xv.y, w1.x, fmaf(xv.x, w0.x, acc[i][0]))));
                acc[i][1] = fmaf(xv.w, w3.y, fmaf(xv.z, w2.y, fmaf(xv.y, w1.y, fmaf(xv.x, w0.y, acc[i][1]))));
                acc[i][2] = fmaf(xv.w, w3.z, fmaf(xv.z, w2.z, fmaf(xv.y, w1.z, fmaf(xv.x, w0.z, acc[i][2]))));
                acc[i][3] = fmaf(xv.w, w3.w, fmaf(xv.z, w2.w, fmaf(xv.y, w1.w, fmaf(xv.x, w0.w, acc[i][3]))));
            }
        }
        __syncthreads();
    }
#pragma unroll
    for (int i = 0; i < 8; ++i) {
        int n = n0 + ng * 8 + i;
        if (n < N) {
            float4 v = {acc[i][0], acc[i][1], acc[i][2], acc[i][3]};
            if (cg < 16) *(float4*)&xl[(long)n * H_DIM + (cg << 2)] = v;
            else         *(float4*)&xr[(long)n * H_DIM + ((cg - 16) << 2)] = v;
        }
    }
}

// ---- Layer 2 GEMM: LDS-tiled.  [N x 32] = H[N x 64] @ [W2l | W2r] ------
#define G2_NT 128
#define G2_XS 68
__global__ __launch_bounds__(256) void k_gemm2t(
        const float* __restrict__ Hm, const float* __restrict__ Wl,
        const float* __restrict__ Wr,
        float* __restrict__ xl, float* __restrict__ xr, int N) {
    __shared__ float Ws[64 * 32];        // 8 KB
    __shared__ float Xs[G2_NT * G2_XS];  // 34.8 KB
    int t = threadIdx.x;
    int n0 = blockIdx.x * G2_NT;
    int validRows = N - n0; if (validRows > G2_NT) validRows = G2_NT;
    // stage W: each matrix 64x16 = 256 float4
    if (t < 256) {
        int kk = t >> 2, c = (t & 3) << 2;
        *(float4*)&Ws[kk * 32 + c]      = *(const float4*)&Wl[kk * K_DIM + c];
        *(float4*)&Ws[kk * 32 + 16 + c] = *(const float4*)&Wr[kk * K_DIM + c];
    }
    // stage X: 128 rows x 16 float4
    for (int i = t; i < 2048; i += 256) {
        int r = i >> 4, c = (i & 15) << 2;
        float4 v = {0.f, 0.f, 0.f, 0.f};
        if (r < validRows)
            v = *(const float4*)&Hm[(long)(n0 + r) * H_DIM + c];
        *(float4*)&Xs[r * G2_XS + c] = v;
    }
    __syncthreads();
    int cg = t & 7;   // 8 col-groups x 4 = 32 cols
    int ng = t >> 3;  // 32 node-groups x 4 = 128 nodes
    float acc[4][4];
#pragma unroll
    for (int i = 0; i < 4; ++i)
#pragma unroll
        for (int c = 0; c < 4; ++c) acc[i][c] = 0.f;
    for (int kk = 0; kk < 64; kk += 4) {
        float4 w0 = *(const float4*)&Ws[(kk + 0) * 32 + (cg << 2)];
        float4 w1 = *(const float4*)&Ws[(kk + 1) * 32 + (cg << 2)];
        float4 w2 = *(const float4*)&Ws[(kk + 2) * 32 + (cg << 2)];
        float4 w3 = *(const float4*)&Ws[(kk + 3) * 32 + (cg << 2)];
#pragma unroll
        for (int i = 0; i < 4; ++i) {
            float4 xv = *(const float4*)&Xs[(ng * 4 + i) * G2_XS + kk];
            acc[i][0] = fmaf(xv.w, w3.x, fmaf(xv.z, w2.x, fmaf(xv.y, w1.x, fmaf(xv.x, w0.x, acc[i][0]))));
            acc[i][1] = fmaf(xv.w, w3.y, fmaf(xv.z, w2.y, fmaf(xv.y, w1.y, fmaf(xv.x, w0.y, acc[i][1]))));
            acc[i][2] = fmaf(xv.w, w3.z, fmaf(xv.z, w2.z, fmaf(xv.y, w1.z, fmaf(xv.x, w0.z, acc[i][2]))));
            acc[i][3] = fmaf(xv.w, w3.w, fmaf(xv.z, w2.w, fmaf(xv.y, w1.w, fmaf(xv.x, w0.w, acc[i][3]))));
        }
    }
#pragma unroll
    for (int i = 0; i < 4; ++i) {
        int n = n0 + ng * 4 + i;
        if (n < N) {
            float4 v = {acc[i][0], acc[i][1], acc[i][2], acc[i][3]};
            if (cg < 4) *(float4*)&xl[(long)n * K_DIM + (cg << 2)] = v;
            else        *(float4*)&xr[(long)n * K_DIM + ((cg - 4) << 2)] = v;
        }
    }
}

// ---- Edge kernel layer 1: one wave/node, lane = h, unroll-2 pipeline ---
__global__ void k_edge1(const float* __restrict__ xl, const float* __restrict__ xr,
                        const float* __restrict__ a1, const float* __restrict__ b1,
                        const int* __restrict__ rowptr, const int* __restrict__ col,
                        float* __restrict__ hout, int N) {
    int n = (int)((blockIdx.x * (unsigned)blockDim.x + threadIdx.x) >> 6);
    int lane = threadIdx.x & 63;
    if (n >= N) return;
    float av = a1[lane];
    float xrd = xr[(long)n * H_DIM + lane];
    float xls = xl[(long)n * H_DIM + lane];
    float t = xls + xrd; t = (t > 0.f) ? t : NEG_SLOPE * t;
    float p = av * t;
#pragma unroll
    for (int off = 32; off; off >>= 1) p += __shfl_xor(p, off);
    float m = p, l = 1.f, o = xls;
    int jb = rowptr[n], je = rowptr[n + 1];
    int j = jb;
    for (; j + 1 < je; j += 2) {
        int s0 = col[j], s1 = col[j + 1];
        float xv0 = xl[(long)s0 * H_DIM + lane];
        float xv1 = xl[(long)s1 * H_DIM + lane];
        float t0 = xv0 + xrd; t0 = (t0 > 0.f) ? t0 : NEG_SLOPE * t0;
        float t1 = xv1 + xrd; t1 = (t1 > 0.f) ? t1 : NEG_SLOPE * t1;
        float e0 = av * t0, e1 = av * t1;
#pragma unroll
        for (int off = 32; off; off >>= 1) {
            e0 += __shfl_xor(e0, off);
            e1 += __shfl_xor(e1, off);
        }
        if (e0 > m) { float c = __expf(m - e0); l = l * c + 1.f; o = o * c + xv0; m = e0; }
        else        { float c = __expf(e0 - m); l += c; o += c * xv0; }
        if (e1 > m) { float c = __expf(m - e1); l = l * c + 1.f; o = o * c + xv1; m = e1; }
        else        { float c = __expf(e1 - m); l += c; o += c * xv1; }
    }
    if (j < je) {
        int s = col[j];
        float xv = xl[(long)s * H_DIM + lane];
        float tt = xv + xrd; tt = (tt > 0.f) ? tt : NEG_SLOPE * tt;
        float e = av * tt;
#pragma unroll
        for (int off = 32; off; off >>= 1) e += __shfl_xor(e, off);
        if (e > m) { float c = __expf(m - e); l = l * c + 1.f; o = o * c + xv; m = e; }
        else       { float c = __expf(e - m); l += c; o += c * xv; }
    }
    float h = o / l + b1[lane];
    h = (h > 0.f) ? h : (__expf(h) - 1.f);   // ELU(alpha=1)
    hout[(long)n * H_DIM + lane] = h;
}

// ---- Edge kernel layer 2: 4 edge-groups/wave (16 lanes = K dim each) ---
__global__ void k_edge2(const float* __restrict__ xl, const float* __restrict__ xr,
                        const float* __restrict__ a2, const float* __restrict__ b2v,
                        const int* __restrict__ rowptr, const int* __restrict__ col,
                        float* __restrict__ out, int N) {
    int n = (int)((blockIdx.x * (unsigned)blockDim.x + threadIdx.x) >> 6);
    int lane = threadIdx.x & 63;
    if (n >= N) return;
    int j = lane & 15, g = lane >> 4;
    float av = a2[j];
    float xrd = xr[(long)n * K_DIM + j];
    float xls = xl[(long)n * K_DIM + j];
    // self-loop handled by group 0 only
    float t = xls + xrd; t = (t > 0.f) ? t : NEG_SLOPE * t;
    float p = av * t;
#pragma unroll
    for (int off = 8; off; off >>= 1) p += __shfl_xor(p, off, 16);
    float m, l, o;
    if (g == 0) { m = p; l = 1.f; o = xls; }
    else        { m = -1e30f; l = 0.f; o = 0.f; }
    int jb = rowptr[n], je = rowptr[n + 1];
    for (int jj = jb + g; jj < je; jj += 4) {
        int s = col[jj];
        float xv = xl[(long)s * K_DIM + j];
        float tt = xv + xrd; tt = (tt > 0.f) ? tt : NEG_SLOPE * tt;
        float e = av * tt;
#pragma unroll
        for (int off = 8; off; off >>= 1) e += __shfl_xor(e, off, 16);
        // branchless online-softmax update (groups diverge, avoid masked 2x)
        float nm = fmaxf(m, e);
        float c1 = __expf(m - nm), c2 = __expf(e - nm);
        l = l * c1 + c2;
        o = o * c1 + c2 * xv;
        m = nm;
    }
    // merge the 4 group-partials (pairwise over lane bits 4,5)
#pragma unroll
    for (int off = 16; off <= 32; off <<= 1) {
        float m2 = __shfl_xor(m, off);
        float l2 = __shfl_xor(l, off);
        float o2 = __shfl_xor(o, off);
        float nm = fmaxf(m, m2);
        float c1 = __expf(m - nm), c2 = __expf(m2 - nm);
        l = l * c1 + l2 * c2;
        o = o * c1 + o2 * c2;
        m = nm;
    }
    float z = o / l + b2v[j];
    float mx = z;
#pragma unroll
    for (int off = 8; off; off >>= 1) mx = fmaxf(mx, __shfl_xor(mx, off, 16));
    float ez = __expf(z - mx);
    float ss = ez;
#pragma unroll
    for (int off = 8; off; off >>= 1) ss += __shfl_xor(ss, off, 16);
    if (lane < 16) out[(long)n * K_DIM + j] = ez / ss;
}

// ---- launch ------------------------------------------------------------
extern "C" void kernel_launch(void* const* d_in, const int* in_sizes, int n_in,
                              void* d_out, int out_size, void* d_ws, size_t ws_size,
                              hipStream_t stream) {
    const float* X   = (const float*)d_in[0];
    const int*   ei  = (const int*)d_in[1];
    const float* W1l = (const float*)d_in[3];
    const float* W1r = (const float*)d_in[4];
    const float* a1  = (const float*)d_in[5];
    const float* b1  = (const float*)d_in[6];
    const float* W2l = (const float*)d_in[7];
    const float* W2r = (const float*)d_in[8];
    const float* a2  = (const float*)d_in[9];
    const float* b2  = (const float*)d_in[10];

    int N = in_sizes[0] / F_DIM;
    int E = in_sizes[1] / 2;
    const int* srcv = ei;
    const int* dstv = ei + E;

    char* w = (char*)d_ws;
    size_t off = 0;
    auto alloc = [&](size_t bytes) -> char* {
        char* p = w + off;
        off = (off + bytes + 255) & ~(size_t)255;
        return p;
    };
    int* counts = (int*)alloc((size_t)2 * N * sizeof(int));  // counts + fill, one memset
    int* fillc  = counts + N;
    int* rowptr = (int*)alloc((size_t)(N + 1) * sizeof(int));
    int* bsum   = (int*)alloc(256 * sizeof(int));
    int* tmp    = (int*)alloc((size_t)N * sizeof(int));
    int* col    = (int*)alloc((size_t)E * sizeof(int));
    float* xl1 = (float*)alloc((size_t)N * H_DIM * sizeof(float));
    float* xr1 = (float*)alloc((size_t)N * H_DIM * sizeof(float));
    float* h1  = (float*)alloc((size_t)N * H_DIM * sizeof(float));
    float* xl2 = (float*)alloc((size_t)N * K_DIM * sizeof(float));
    float* xr2 = (float*)alloc((size_t)N * K_DIM * sizeof(float));

    hipMemsetAsync(counts, 0, (size_t)2 * N * sizeof(int), stream);

    const int tb = 256;
    k_degree<<<(E + tb - 1) / tb, tb, 0, stream>>>(dstv, counts, E);
    int nbA = (N + 1023) / 1024;
    k_scanA<<<nbA, 256, 0, stream>>>(counts, tmp, bsum, N);
    k_scanB<<<1, 256, 0, stream>>>(bsum, nbA);
    k_scanC<<<(N + tb - 1) / tb, tb, 0, stream>>>(tmp, bsum, rowptr, N);
    k_fill<<<(E + tb - 1) / tb, tb, 0, stream>>>(srcv, dstv, rowptr, fillc, col, E);

    int g1Blocks = (N + G1_NT - 1) / G1_NT;
    k_gemm1t<<<g1Blocks, 256, 0, stream>>>(X, W1l, W1r, xl1, xr1, N);
    int nodeBlocks = (N + 3) / 4;  // 4 waves (nodes) per 256-thread block
    k_edge1<<<nodeBlocks, 256, 0, stream>>>(xl1, xr1, a1, b1, rowptr, col, h1, N);
    int g2Blocks = (N + G2_NT - 1) / G2_NT;
    k_gemm2t<<<g2Blocks, 256, 0, stream>>>(h1, W2l, W2r, xl2, xr2, N);
    k_edge2<<<nodeBlocks, 256, 0, stream>>>(xl2, xr2, a2, b2, rowptr, col,
                                            (float*)d_out, N);
}

// Round 4
// 495.988 us; speedup vs baseline: 1.9103x; 1.0775x over previous
//
#include <hip/hip_runtime.h>
#include <stdint.h>

#define F_DIM 128
#define H_DIM 64
#define K_DIM 16
#define NEG_SLOPE 0.2f

// ---- CSR construction (self-loops included: slot 0 of each row) --------
__global__ void k_init(int* __restrict__ counts, int* __restrict__ fillc, int N) {
    int i = blockIdx.x * 256 + threadIdx.x;
    if (i < N) { counts[i] = 1; fillc[i] = 0; }
}

__global__ void k_degree(const int* __restrict__ dst, int* __restrict__ counts, int E) {
    int e = blockIdx.x * 256 + threadIdx.x;
    if (e < E) atomicAdd(&counts[dst[e]], 1);
}

__global__ void k_scanA(const int* __restrict__ counts, int* __restrict__ tmp,
                        int* __restrict__ bsum, int N) {
    __shared__ int sh[256];
    int t = threadIdx.x, b = blockIdx.x;
    int base = b * 1024 + t * 4;
    int c0 = (base + 0 < N) ? counts[base + 0] : 0;
    int c1 = (base + 1 < N) ? counts[base + 1] : 0;
    int c2 = (base + 2 < N) ? counts[base + 2] : 0;
    int c3 = (base + 3 < N) ? counts[base + 3] : 0;
    int s = c0 + c1 + c2 + c3;
    sh[t] = s;
    __syncthreads();
    for (int off = 1; off < 256; off <<= 1) {
        int v = (t >= off) ? sh[t - off] : 0;
        __syncthreads();
        sh[t] += v;
        __syncthreads();
    }
    int excl = sh[t] - s;
    int r0 = excl + c0, r1 = r0 + c1, r2 = r1 + c2, r3 = r2 + c3;
    if (base + 0 < N) tmp[base + 0] = r0;
    if (base + 1 < N) tmp[base + 1] = r1;
    if (base + 2 < N) tmp[base + 2] = r2;
    if (base + 3 < N) tmp[base + 3] = r3;
    if (t == 255) bsum[b] = sh[255];
}

__global__ void k_scanB(int* __restrict__ bsum, int NB) {
    __shared__ int sh[256];
    int t = threadIdx.x;
    int v = (t < NB) ? bsum[t] : 0;
    sh[t] = v;
    __syncthreads();
    for (int off = 1; off < 256; off <<= 1) {
        int x = (t >= off) ? sh[t - off] : 0;
        __syncthreads();
        sh[t] += x;
        __syncthreads();
    }
    if (t < NB) bsum[t] = sh[t];
}

__global__ void k_scanC(const int* __restrict__ tmp, const int* __restrict__ bsum,
                        int* __restrict__ rowptr, int N) {
    int i = blockIdx.x * 256 + threadIdx.x;
    if (i < N) {
        int b = i >> 10;
        int off = (b > 0) ? bsum[b - 1] : 0;
        rowptr[i + 1] = tmp[i] + off;
    }
    if (i == 0) rowptr[0] = 0;
}

__global__ void k_self(const int* __restrict__ rowptr, int* __restrict__ col, int N) {
    int i = blockIdx.x * 256 + threadIdx.x;
    if (i < N) col[rowptr[i]] = i;
}

__global__ void k_fill(const int* __restrict__ src, const int* __restrict__ dst,
                       const int* __restrict__ rowptr, int* __restrict__ fillc,
                       int* __restrict__ col, int E) {
    int e = blockIdx.x * 256 + threadIdx.x;
    if (e < E) {
        int d = dst[e];
        int pos = rowptr[d] + 1 + atomicAdd(&fillc[d], 1);
        col[pos] = src[e];
    }
}

// ---- Layer 1 GEMM: LDS-tiled.  Y[N x 128] = X[N x 128] @ [Wl | Wr]  ----
#define G1_NT 64
#define G1_XS 68
__global__ __launch_bounds__(256) void k_gemm1t(
        const float* __restrict__ X, const float* __restrict__ Wl,
        const float* __restrict__ Wr,
        float* __restrict__ xl, float* __restrict__ xr, int N) {
    __shared__ float Ws[64 * 128];
    __shared__ float Xs[G1_NT * G1_XS];
    int t = threadIdx.x;
    int n0 = blockIdx.x * G1_NT;
    int validRows = N - n0; if (validRows > G1_NT) validRows = G1_NT;
    int cg = t & 31;
    int ng = t >> 5;
    float acc[8][4];
#pragma unroll
    for (int i = 0; i < 8; ++i)
#pragma unroll
        for (int c = 0; c < 4; ++c) acc[i][c] = 0.f;

    for (int kt = 0; kt < 2; ++kt) {
        int kbase = kt * 64;
        for (int i = t; i < 1024; i += 256) {
            int kk = i >> 4, c = (i & 15) << 2;
            *(float4*)&Ws[kk * 128 + c] =
                *(const float4*)&Wl[(kbase + kk) * H_DIM + c];
            *(float4*)&Ws[kk * 128 + 64 + c] =
                *(const float4*)&Wr[(kbase + kk) * H_DIM + c];
        }
        for (int i = t; i < 1024; i += 256) {
            int r = i >> 4, c = (i & 15) << 2;
            float4 v = {0.f, 0.f, 0.f, 0.f};
            if (r < validRows)
                v = *(const float4*)&X[(long)(n0 + r) * F_DIM + kbase + c];
            *(float4*)&Xs[r * G1_XS + c] = v;
        }
        __syncthreads();
        for (int kk = 0; kk < 64; kk += 4) {
            float4 w0 = *(const float4*)&Ws[(kk + 0) * 128 + (cg << 2)];
            float4 w1 = *(const float4*)&Ws[(kk + 1) * 128 + (cg << 2)];
            float4 w2 = *(const float4*)&Ws[(kk + 2) * 128 + (cg << 2)];
            float4 w3 = *(const float4*)&Ws[(kk + 3) * 128 + (cg << 2)];
#pragma unroll
            for (int i = 0; i < 8; ++i) {
                float4 xv = *(const float4*)&Xs[(ng * 8 + i) * G1_XS + kk];
                acc[i][0] = fmaf(xv.w, w3.x, fmaf(xv.z, w2.x, fmaf(xv.y, w1.x, fmaf(xv.x, w0.x, acc[i][0]))));
                acc[i][1] = fmaf(xv.w, w3.y, fmaf(xv.z, w2.y, fmaf(xv.y, w1.y, fmaf(xv.x, w0.y, acc[i][1]))));
                acc[i][2] = fmaf(xv.w, w3.z, fmaf(xv.z, w2.z, fmaf(xv.y, w1.z, fmaf(xv.x, w0.z, acc[i][2]))));
                acc[i][3] = fmaf(xv.w, w3.w, fmaf(xv.z, w2.w, fmaf(xv.y, w1.w, fmaf(xv.x, w0.w, acc[i][3]))));
            }
        }
        __syncthreads();
    }
#pragma unroll
    for (int i = 0; i < 8; ++i) {
        int n = n0 + ng * 8 + i;
        if (n < N) {
            float4 v = {acc[i][0], acc[i][1], acc[i][2], acc[i][3]};
            if (cg < 16) *(float4*)&xl[(long)n * H_DIM + (cg << 2)] = v;
            else         *(float4*)&xr[(long)n * H_DIM + ((cg - 16) << 2)] = v;
        }
    }
}

// ---- Layer 2 GEMM: LDS-tiled.  [N x 32] = H[N x 64] @ [W2l | W2r] ------
#define G2_NT 128
#define G2_XS 68
__global__ __launch_bounds__(256) void k_gemm2t(
        const float* __restrict__ Hm, const float* __restrict__ Wl,
        const float* __restrict__ Wr,
        float* __restrict__ xl, float* __restrict__ xr, int N) {
    __shared__ float Ws[64 * 32];
    __shared__ float Xs[G2_NT * G2_XS];
    int t = threadIdx.x;
    int n0 = blockIdx.x * G2_NT;
    int validRows = N - n0; if (validRows > G2_NT) validRows = G2_NT;
    if (t < 256) {
        int kk = t >> 2, c = (t & 3) << 2;
        *(float4*)&Ws[kk * 32 + c]      = *(const float4*)&Wl[kk * K_DIM + c];
        *(float4*)&Ws[kk * 32 + 16 + c] = *(const float4*)&Wr[kk * K_DIM + c];
    }
    for (int i = t; i < 2048; i += 256) {
        int r = i >> 4, c = (i & 15) << 2;
        float4 v = {0.f, 0.f, 0.f, 0.f};
        if (r < validRows)
            v = *(const float4*)&Hm[(long)(n0 + r) * H_DIM + c];
        *(float4*)&Xs[r * G2_XS + c] = v;
    }
    __syncthreads();
    int cg = t & 7;
    int ng = t >> 3;
    float acc[4][4];
#pragma unroll
    for (int i = 0; i < 4; ++i)
#pragma unroll
        for (int c = 0; c < 4; ++c) acc[i][c] = 0.f;
    for (int kk = 0; kk < 64; kk += 4) {
        float4 w0 = *(const float4*)&Ws[(kk + 0) * 32 + (cg << 2)];
        float4 w1 = *(const float4*)&Ws[(kk + 1) * 32 + (cg << 2)];
        float4 w2 = *(const float4*)&Ws[(kk + 2) * 32 + (cg << 2)];
        float4 w3 = *(const float4*)&Ws[(kk + 3) * 32 + (cg << 2)];
#pragma unroll
        for (int i = 0; i < 4; ++i) {
            float4 xv = *(const float4*)&Xs[(ng * 4 + i) * G2_XS + kk];
            acc[i][0] = fmaf(xv.w, w3.x, fmaf(xv.z, w2.x, fmaf(xv.y, w1.x, fmaf(xv.x, w0.x, acc[i][0]))));
            acc[i][1] = fmaf(xv.w, w3.y, fmaf(xv.z, w2.y, fmaf(xv.y, w1.y, fmaf(xv.x, w0.y, acc[i][1]))));
            acc[i][2] = fmaf(xv.w, w3.z, fmaf(xv.z, w2.z, fmaf(xv.y, w1.z, fmaf(xv.x, w0.z, acc[i][2]))));
            acc[i][3] = fmaf(xv.w, w3.w, fmaf(xv.z, w2.w, fmaf(xv.y, w1.w, fmaf(xv.x, w0.w, acc[i][3]))));
        }
    }
#pragma unroll
    for (int i = 0; i < 4; ++i) {
        int n = n0 + ng * 4 + i;
        if (n < N) {
            float4 v = {acc[i][0], acc[i][1], acc[i][2], acc[i][3]};
            if (cg < 4) *(float4*)&xl[(long)n * K_DIM + (cg << 2)] = v;
            else        *(float4*)&xr[(long)n * K_DIM + ((cg - 4) << 2)] = v;
        }
    }
}

// ---- Attention layer 1: wave=node, 4 edge-groups x 16 lanes (float4) ---
__global__ void k_att1(const float* __restrict__ xl, const float* __restrict__ xr,
                       const float* __restrict__ a1, const float* __restrict__ b1,
                       const int* __restrict__ rowptr, const int* __restrict__ col,
                       float* __restrict__ hout, int N) {
    int n = (int)((blockIdx.x * (unsigned)blockDim.x + threadIdx.x) >> 6);
    int lane = threadIdx.x & 63;
    if (n >= N) return;
    int q = lane & 15;   // dim-group: dims 4q..4q+3
    int g = lane >> 4;   // edge group 0..3
    const float4* xl4 = (const float4*)xl;
    float4 av  = ((const float4*)a1)[q];
    float4 xrv = ((const float4*)xr)[(long)n * 16 + q];
    int jb = rowptr[n], je = rowptr[n + 1];
    float m = -1e30f, l = 0.f;
    float4 o = {0.f, 0.f, 0.f, 0.f};
    for (int j = jb + g; j < je; j += 4) {
        int s = col[j];
        float4 xv = xl4[(long)s * 16 + q];
        float tx = xv.x + xrv.x; tx = (tx > 0.f) ? tx : NEG_SLOPE * tx;
        float ty = xv.y + xrv.y; ty = (ty > 0.f) ? ty : NEG_SLOPE * ty;
        float tz = xv.z + xrv.z; tz = (tz > 0.f) ? tz : NEG_SLOPE * tz;
        float tw = xv.w + xrv.w; tw = (tw > 0.f) ? tw : NEG_SLOPE * tw;
        float e = fmaf(av.x, tx, fmaf(av.y, ty, fmaf(av.z, tz, av.w * tw)));
#pragma unroll
        for (int off = 1; off < 16; off <<= 1) e += __shfl_xor(e, off, 16);
        float nm = fmaxf(m, e);
        float c1 = __expf(m - nm), c2 = __expf(e - nm);
        l = l * c1 + c2;
        o.x = o.x * c1 + c2 * xv.x;
        o.y = o.y * c1 + c2 * xv.y;
        o.z = o.z * c1 + c2 * xv.z;
        o.w = o.w * c1 + c2 * xv.w;
        m = nm;
    }
    // merge the 4 edge-groups (lane bits 4,5)
#pragma unroll
    for (int off = 16; off <= 32; off <<= 1) {
        float m2 = __shfl_xor(m, off);
        float l2 = __shfl_xor(l, off);
        float ox = __shfl_xor(o.x, off);
        float oy = __shfl_xor(o.y, off);
        float oz = __shfl_xor(o.z, off);
        float ow = __shfl_xor(o.w, off);
        float nm = fmaxf(m, m2);
        float c1 = __expf(m - nm), c2 = __expf(m2 - nm);
        l = l * c1 + l2 * c2;
        o.x = o.x * c1 + ox * c2;
        o.y = o.y * c1 + oy * c2;
        o.z = o.z * c1 + oz * c2;
        o.w = o.w * c1 + ow * c2;
        m = nm;
    }
    if (g == 0) {
        float4 bv = ((const float4*)b1)[q];
        float rl = 1.f / l;
        float4 h;
        h.x = o.x * rl + bv.x; h.x = (h.x > 0.f) ? h.x : (__expf(h.x) - 1.f);
        h.y = o.y * rl + bv.y; h.y = (h.y > 0.f) ? h.y : (__expf(h.y) - 1.f);
        h.z = o.z * rl + bv.z; h.z = (h.z > 0.f) ? h.z : (__expf(h.z) - 1.f);
        h.w = o.w * rl + bv.w; h.w = (h.w > 0.f) ? h.w : (__expf(h.w) - 1.f);
        ((float4*)hout)[(long)n * 16 + q] = h;
    }
}

// ---- Attention layer 2 + softmax: 16 edge-groups x 4 lanes (float4) ----
__global__ void k_att2(const float* __restrict__ xl, const float* __restrict__ xr,
                       const float* __restrict__ a2, const float* __restrict__ b2v,
                       const int* __restrict__ rowptr, const int* __restrict__ col,
                       float* __restrict__ out, int N) {
    int n = (int)((blockIdx.x * (unsigned)blockDim.x + threadIdx.x) >> 6);
    int lane = threadIdx.x & 63;
    if (n >= N) return;
    int q = lane & 3;    // dims 4q..4q+3 (16 dims over 4 lanes)
    int g = lane >> 2;   // edge group 0..15
    const float4* xl4 = (const float4*)xl;
    float4 av  = ((const float4*)a2)[q];
    float4 xrv = ((const float4*)xr)[(long)n * 4 + q];
    int jb = rowptr[n], je = rowptr[n + 1];
    float m = -1e30f, l = 0.f;
    float4 o = {0.f, 0.f, 0.f, 0.f};
    for (int j = jb + g; j < je; j += 16) {
        int s = col[j];
        float4 xv = xl4[(long)s * 4 + q];
        float tx = xv.x + xrv.x; tx = (tx > 0.f) ? tx : NEG_SLOPE * tx;
        float ty = xv.y + xrv.y; ty = (ty > 0.f) ? ty : NEG_SLOPE * ty;
        float tz = xv.z + xrv.z; tz = (tz > 0.f) ? tz : NEG_SLOPE * tz;
        float tw = xv.w + xrv.w; tw = (tw > 0.f) ? tw : NEG_SLOPE * tw;
        float e = fmaf(av.x, tx, fmaf(av.y, ty, fmaf(av.z, tz, av.w * tw)));
        e += __shfl_xor(e, 1, 4);
        e += __shfl_xor(e, 2, 4);
        float nm = fmaxf(m, e);
        float c1 = __expf(m - nm), c2 = __expf(e - nm);
        l = l * c1 + c2;
        o.x = o.x * c1 + c2 * xv.x;
        o.y = o.y * c1 + c2 * xv.y;
        o.z = o.z * c1 + c2 * xv.z;
        o.w = o.w * c1 + c2 * xv.w;
        m = nm;
    }
    // merge the 16 edge-groups (lane bits 2..5)
#pragma unroll
    for (int off = 4; off <= 32; off <<= 1) {
        float m2 = __shfl_xor(m, off);
        float l2 = __shfl_xor(l, off);
        float ox = __shfl_xor(o.x, off);
        float oy = __shfl_xor(o.y, off);
        float oz = __shfl_xor(o.z, off);
        float ow = __shfl_xor(o.w, off);
        float nm = fmaxf(m, m2);
        float c1 = __expf(m - nm), c2 = __expf(m2 - nm);
        l = l * c1 + l2 * c2;
        o.x = o.x * c1 + ox * c2;
        o.y = o.y * c1 + oy * c2;
        o.z = o.z * c1 + oz * c2;
        o.w = o.w * c1 + ow * c2;
        m = nm;
    }
    if (g == 0) {
        float4 bv = ((const float4*)b2v)[q];
        float rl = 1.f / l;
        float4 z;
        z.x = o.x * rl + bv.x;
        z.y = o.y * rl + bv.y;
        z.z = o.z * rl + bv.z;
        z.w = o.w * rl + bv.w;
        // softmax over 16 dims = 4 lanes x 4 comps
        float mx = fmaxf(fmaxf(z.x, z.y), fmaxf(z.z, z.w));
        mx = fmaxf(mx, __shfl_xor(mx, 1, 4));
        mx = fmaxf(mx, __shfl_xor(mx, 2, 4));
        float4 ez;
        ez.x = __expf(z.x - mx); ez.y = __expf(z.y - mx);
        ez.z = __expf(z.z - mx); ez.w = __expf(z.w - mx);
        float ss = ez.x + ez.y + ez.z + ez.w;
        ss += __shfl_xor(ss, 1, 4);
        ss += __shfl_xor(ss, 2, 4);
        float rs = 1.f / ss;
        ez.x *= rs; ez.y *= rs; ez.z *= rs; ez.w *= rs;
        ((float4*)out)[(long)n * 4 + q] = ez;
    }
}

// ---- launch ------------------------------------------------------------
extern "C" void kernel_launch(void* const* d_in, const int* in_sizes, int n_in,
                              void* d_out, int out_size, void* d_ws, size_t ws_size,
                              hipStream_t stream) {
    const float* X   = (const float*)d_in[0];
    const int*   ei  = (const int*)d_in[1];
    const float* W1l = (const float*)d_in[3];
    const float* W1r = (const float*)d_in[4];
    const float* a1  = (const float*)d_in[5];
    const float* b1  = (const float*)d_in[6];
    const float* W2l = (const float*)d_in[7];
    const float* W2r = (const float*)d_in[8];
    const float* a2  = (const float*)d_in[9];
    const float* b2  = (const float*)d_in[10];

    int N = in_sizes[0] / F_DIM;
    int E = in_sizes[1] / 2;
    int M = E + N;  // CSR entries incl. self-loops
    const int* srcv = ei;
    const int* dstv = ei + E;

    char* w = (char*)d_ws;
    size_t off = 0;
    auto alloc = [&](size_t bytes) -> char* {
        char* p = w + off;
        off = (off + bytes + 255) & ~(size_t)255;
        return p;
    };
    int* counts = (int*)alloc((size_t)N * sizeof(int));
    int* fillc  = (int*)alloc((size_t)N * sizeof(int));
    int* rowptr = (int*)alloc((size_t)(N + 1) * sizeof(int));
    int* bsum   = (int*)alloc(256 * sizeof(int));
    int* tmp    = (int*)alloc((size_t)N * sizeof(int));
    int* col    = (int*)alloc((size_t)M * sizeof(int));
    float* xl1 = (float*)alloc((size_t)N * H_DIM * sizeof(float));
    float* xr1 = (float*)alloc((size_t)N * H_DIM * sizeof(float));
    float* h1  = (float*)alloc((size_t)N * H_DIM * sizeof(float));
    float* xl2 = (float*)alloc((size_t)N * K_DIM * sizeof(float));
    float* xr2 = (float*)alloc((size_t)N * K_DIM * sizeof(float));

    const int tb = 256;
    int nBlk = (N + tb - 1) / tb;
    k_init<<<nBlk, tb, 0, stream>>>(counts, fillc, N);
    k_degree<<<(E + tb - 1) / tb, tb, 0, stream>>>(dstv, counts, E);
    int nbA = (N + 1023) / 1024;
    k_scanA<<<nbA, 256, 0, stream>>>(counts, tmp, bsum, N);
    k_scanB<<<1, 256, 0, stream>>>(bsum, nbA);
    k_scanC<<<nBlk, tb, 0, stream>>>(tmp, bsum, rowptr, N);
    k_self<<<nBlk, tb, 0, stream>>>(rowptr, col, N);
    k_fill<<<(E + tb - 1) / tb, tb, 0, stream>>>(srcv, dstv, rowptr, fillc, col, E);

    int g1Blocks = (N + G1_NT - 1) / G1_NT;
    k_gemm1t<<<g1Blocks, 256, 0, stream>>>(X, W1l, W1r, xl1, xr1, N);
    int nodeBlocks = (N + 3) / 4;  // 4 waves (nodes) per 256-thread block
    k_att1<<<nodeBlocks, 256, 0, stream>>>(xl1, xr1, a1, b1, rowptr, col, h1, N);
    int g2Blocks = (N + G2_NT - 1) / G2_NT;
    k_gemm2t<<<g2Blocks, 256, 0, stream>>>(h1, W2l, W2r, xl2, xr2, N);
    k_att2<<<nodeBlocks, 256, 0, stream>>>(xl2, xr2, a2, b2, rowptr, col,
                                           (float*)d_out, N);
}